// Round 17
// baseline (302.076 us; speedup 1.0000x reference)
//
#include <hip/hip_runtime.h>

// irreps linear: 256x0e + 128x1o + 64x2e, shared weights, bias on 0e.
// x: (200000, 960) f32; w: 86016 f32; b: 256 f32; out: (200000, 960) f32.
//
// Round 17 = R16 (co-temporal family dispatch, 287.5us) + occupancy bump:
// 5 roles per 32-row tile group (bid%5): fam0 keeps its 32-row block
// (R16 body verbatim, 33.3KB LDS); fam1 and fam2 split into two 16-row
// blocks each (R9 bodies verbatim, 24.8/20.7KB). Max static LDS drops
// 49.7KB -> 33.3KB => 4 blocks/CU instead of 3 (+33% co-resident work to
// cover stage-drains and barrier lulls). Co-temporal sequential read/write
// streams preserved (roles of one tile group dispatch adjacently).

typedef short frag8 __attribute__((ext_vector_type(8)));   // 8 bf16
typedef float f32x4 __attribute__((ext_vector_type(4)));
typedef unsigned int u32;
typedef u32 u32x4 __attribute__((ext_vector_type(4)));

#define ST0 1040   // 65 chunks * 16B (64 data + 1 pad)
#define ST1 1552   // 97 chunks
#define ST2 1296   // 81 chunks

static __device__ __forceinline__ short f2bf(float f) {   // prep kernel only
    union { float f; unsigned u; } v; v.f = f;
    unsigned r = (v.u + 0x7FFFu + ((v.u >> 16) & 1u)) >> 16;  // RNE
    return (short)r;
}

static __device__ __forceinline__ u32 cvtpk(float lo, float hi) {
    u32 r;
    asm("v_cvt_pk_bf16_f32 %0, %1, %2" : "=v"(r) : "v"(lo), "v"(hi));
    return r;
}

static __device__ __forceinline__ frag8 asfrag(u32x4 u) {
    union { u32x4 u; frag8 f; } t; t.u = u; return t.f;
}

#define MFMA(a, b, c) __builtin_amdgcn_mfma_f32_16x16x32_bf16((a), (b), (c), 0, 0, 0)

// ---- weight prep: unchanged (validated rounds 1-16). frag f, lane l, reg j:
// k = 32*s + 4*(l>>4) + (j&3) + 16*(j>>2), w = nt*16 + (l&15).
__global__ __launch_bounds__(256) void prep_kernel(const float* __restrict__ w,
                                                   short* __restrict__ wf) {
    int e = blockIdx.x * 256 + threadIdx.x;   // 0..86015
    int f = e >> 9;
    int r = e & 511;
    int l = r >> 3, j = r & 7;
    int l15 = l & 15, lg = l >> 4;
    int kk = 4 * lg + (j & 3) + 16 * (j >> 2);
    int u, wc, woff, mul; float scale;
    if (f < 128) {
        int nt = f >> 3, s = f & 7;
        u = 32 * s + kk; wc = nt * 16 + l15; woff = 0;     mul = 256; scale = 0.0625f;
    } else if (f < 160) {
        int g = f - 128, nt = g >> 2, s = g & 3;
        u = 32 * s + kk; wc = nt * 16 + l15; woff = 65536; mul = 128; scale = 0.088388347648318447f;
    } else {
        int g = f - 160, nt = g >> 1, s = g & 1;
        u = 32 * s + kk; wc = nt * 16 + l15; woff = 81920; mul = 64;  scale = 0.125f;
    }
    wf[e] = f2bf(scale * w[woff + u * mul + wc]);
}

static __device__ __forceinline__ void gload_lds16(const void* g, void* l) {
    __builtin_amdgcn_global_load_lds(
        (const __attribute__((address_space(1))) unsigned int*)g,
        (__attribute__((address_space(3))) unsigned int*)l, 16, 0, 0);
}

__global__ __launch_bounds__(256) void lin_g5(const float* __restrict__ x,
                                              const short* __restrict__ wf,
                                              const float* __restrict__ bias,
                                              float* __restrict__ out) {
    __shared__ __align__(16) char smem[32 * ST0];   // 33280 B -> 4 blk/CU
    const int tid = threadIdx.x, lane = tid & 63, wv = tid >> 6;
    const int l15 = lane & 15, lg = lane >> 4;
    const int bid = blockIdx.x;
    const int role = bid % 5;                       // role varies FASTEST
    const long tile32 = bid / 5;
    const frag8* __restrict__ wfr = (const frag8*)wf;

    if (role == 0) {
        // ======== fam0, 32 rows (R16 body verbatim): cols 0..255, K=256 ====
        const long rowbase = tile32 * 32;
        const char* __restrict__ xb = (const char*)x + rowbase * 3840;
        char* __restrict__ ob = (char*)out + rowbase * 3840;
        f32x4 bv[4];
        #pragma unroll
        for (int q = 0; q < 4; ++q)
            bv[q] = *(const f32x4*)(bias + (4 * wv + q) * 16 + 4 * lg);
        #pragma unroll
        for (int r8 = 0; r8 < 8; ++r8) {
            int r = 8 * wv + r8;
            gload_lds16(xb + (long)r * 3840 + (long)lane * 16, smem + r * ST0);
        }
        __syncthreads();   // S1: stage drained

        const char* sbA = smem + l15 * ST0;
        frag8 a0[8];
        #pragma unroll
        for (int s = 0; s < 8; ++s) {
            const f32x4 v0 = *(const f32x4*)(sbA + (8 * s + lg) * 16);
            const f32x4 v1 = *(const f32x4*)(sbA + (8 * s + 4 + lg) * 16);
            u32x4 t = { cvtpk(v0[0], v0[1]), cvtpk(v0[2], v0[3]),
                        cvtpk(v1[0], v1[1]), cvtpk(v1[2], v1[3]) };
            a0[s] = asfrag(t);
        }
        __syncthreads();   // S2: rows 0-15 reads done

        #pragma unroll
        for (int q = 0; q < 4; ++q) {
            const int nt = 4 * wv + q;
            f32x4 acc = {0.f, 0.f, 0.f, 0.f};
            #pragma unroll
            for (int s = 0; s < 8; ++s)
                acc = MFMA(wfr[(nt * 8 + s) * 64 + lane], a0[s], acc);
            const int g0 = nt * 4 + lg;
            *(f32x4*)(smem + l15 * ST0 + g0 * 16) = acc + bv[q];
        }
        const char* sbB = smem + (16 + l15) * ST0;
        frag8 a0b[8];
        #pragma unroll
        for (int s = 0; s < 8; ++s) {
            const f32x4 v0 = *(const f32x4*)(sbB + (8 * s + lg) * 16);
            const f32x4 v1 = *(const f32x4*)(sbB + (8 * s + 4 + lg) * 16);
            u32x4 t = { cvtpk(v0[0], v0[1]), cvtpk(v0[2], v0[3]),
                        cvtpk(v1[0], v1[1]), cvtpk(v1[2], v1[3]) };
            a0b[s] = asfrag(t);
        }
        __syncthreads();   // S3: rows 16-31 reads done

        #pragma unroll
        for (int q = 0; q < 4; ++q) {
            const int nt = 4 * wv + q;
            f32x4 acc = {0.f, 0.f, 0.f, 0.f};
            #pragma unroll
            for (int s = 0; s < 8; ++s)
                acc = MFMA(wfr[(nt * 8 + s) * 64 + lane], a0b[s], acc);
            const int g0 = nt * 4 + lg;
            *(f32x4*)(smem + (16 + l15) * ST0 + g0 * 16) = acc + bv[q];
        }
        __syncthreads();   // S4: all pieces written

        #pragma unroll
        for (int j = 0; j < 8; ++j) {
            int c = j * 256 + tid, r = c >> 6, g = c & 63;
            f32x4 v = *(const f32x4*)(smem + r * ST0 + g * 16);
            *(f32x4*)(ob + (long)r * 3840 + g * 16) = v;
        }
    } else if (role <= 2) {
        // ===== fam1, 16 rows (R9 lin_f1 body verbatim): cols 256..639 ======
        const long rowbase = tile32 * 32 + (role == 2 ? 16 : 0);
        const char* __restrict__ xb = (const char*)x + rowbase * 3840;
        char* __restrict__ ob = (char*)out + rowbase * 3840;

        frag8 w1[8];
        #pragma unroll
        for (int q = 0; q < 2; ++q)
            #pragma unroll
            for (int s = 0; s < 4; ++s)
                w1[q * 4 + s] = wfr[(128 + (2 * wv + q) * 4 + s) * 64 + lane];

        #pragma unroll
        for (int r4 = 0; r4 < 4; ++r4) {
            int r = 4 * wv + r4;
            gload_lds16(xb + (long)r * 3840 + 1024 + (long)lane * 16, smem + r * ST1);
            if (lane < 32)
                gload_lds16(xb + (long)r * 3840 + 2048 + (long)lane * 16,
                            smem + r * ST1 + 1024);
        }
        __syncthreads();   // S1

        const char* sb = smem + l15 * ST1;
        u32x4 a1u[12];
        #pragma unroll
        for (int s = 0; s < 4; ++s) {
            #pragma unroll
            for (int h = 0; h < 2; ++h) {
                const int cb = 24 * s + 12 * h + 3 * lg;
                const f32x4 q0 = *(const f32x4*)(sb + (cb    ) * 16);
                const f32x4 q1 = *(const f32x4*)(sb + (cb + 1) * 16);
                const f32x4 q2 = *(const f32x4*)(sb + (cb + 2) * 16);
                a1u[0 + s][2 * h]     = cvtpk(q0[0], q0[3]);
                a1u[0 + s][2 * h + 1] = cvtpk(q1[2], q2[1]);
                a1u[4 + s][2 * h]     = cvtpk(q0[1], q1[0]);
                a1u[4 + s][2 * h + 1] = cvtpk(q1[3], q2[2]);
                a1u[8 + s][2 * h]     = cvtpk(q0[2], q1[1]);
                a1u[8 + s][2 * h + 1] = cvtpk(q2[0], q2[3]);
            }
        }
        f32x4 sv[2][3];
        #pragma unroll
        for (int q = 0; q < 2; ++q) {
            f32x4 c0 = {0.f,0.f,0.f,0.f}, c1 = {0.f,0.f,0.f,0.f}, c2 = {0.f,0.f,0.f,0.f};
            #pragma unroll
            for (int s = 0; s < 4; ++s) {
                frag8 bw = w1[q * 4 + s];
                c0 = MFMA(bw, asfrag(a1u[0 + s]), c0);
                c1 = MFMA(bw, asfrag(a1u[4 + s]), c1);
                c2 = MFMA(bw, asfrag(a1u[8 + s]), c2);
            }
            sv[q][0] = (f32x4){c0[0], c1[0], c2[0], c0[1]};
            sv[q][1] = (f32x4){c1[1], c2[1], c0[2], c1[2]};
            sv[q][2] = (f32x4){c2[2], c0[3], c1[3], c2[3]};
        }
        __syncthreads();   // S2
        #pragma unroll
        for (int q = 0; q < 2; ++q) {
            const int g0 = 3 * ((2 * wv + q) * 4 + lg);
            #pragma unroll
            for (int i = 0; i < 3; ++i)
                *(f32x4*)(smem + l15 * ST1 + (g0 + i) * 16) = sv[q][i];
        }
        __syncthreads();   // S3
        #pragma unroll
        for (int j = 0; j < 6; ++j) {
            int c = j * 256 + tid, r = c / 96, g = c - r * 96;
            f32x4 v = *(const f32x4*)(smem + r * ST1 + g * 16);
            *(f32x4*)(ob + (long)r * 3840 + 1024 + g * 16) = v;
        }
    } else {
        // ===== fam2, 16 rows (R9 lin_f2 body verbatim): cols 640..959 ======
        const long rowbase = tile32 * 32 + (role == 4 ? 16 : 0);
        const char* __restrict__ xb = (const char*)x + rowbase * 3840;
        char* __restrict__ ob = (char*)out + rowbase * 3840;

        frag8 w2[2];
        #pragma unroll
        for (int s = 0; s < 2; ++s)
            w2[s] = wfr[(160 + wv * 2 + s) * 64 + lane];

        #pragma unroll
        for (int r4 = 0; r4 < 4; ++r4) {
            int r = 4 * wv + r4;
            gload_lds16(xb + (long)r * 3840 + 2560 + (long)lane * 16, smem + r * ST2);
            if (lane < 16)
                gload_lds16(xb + (long)r * 3840 + 3584 + (long)lane * 16,
                            smem + r * ST2 + 1024);
        }
        __syncthreads();   // S1

        const char* sb = smem + l15 * ST2;
        u32x4 a2u[10];
        #pragma unroll
        for (int s = 0; s < 2; ++s) {
            #pragma unroll
            for (int h = 0; h < 2; ++h) {
                const int cb = 40 * s + 20 * h + 5 * lg;
                const f32x4 q0 = *(const f32x4*)(sb + (cb    ) * 16);
                const f32x4 q1 = *(const f32x4*)(sb + (cb + 1) * 16);
                const f32x4 q2 = *(const f32x4*)(sb + (cb + 2) * 16);
                const f32x4 q3 = *(const f32x4*)(sb + (cb + 3) * 16);
                const f32x4 q4 = *(const f32x4*)(sb + (cb + 4) * 16);
                a2u[0 + s][2 * h]     = cvtpk(q0[0], q1[1]);
                a2u[0 + s][2 * h + 1] = cvtpk(q2[2], q3[3]);
                a2u[2 + s][2 * h]     = cvtpk(q0[1], q1[2]);
                a2u[2 + s][2 * h + 1] = cvtpk(q2[3], q4[0]);
                a2u[4 + s][2 * h]     = cvtpk(q0[2], q1[3]);
                a2u[4 + s][2 * h + 1] = cvtpk(q3[0], q4[1]);
                a2u[6 + s][2 * h]     = cvtpk(q0[3], q2[0]);
                a2u[6 + s][2 * h + 1] = cvtpk(q3[1], q4[2]);
                a2u[8 + s][2 * h]     = cvtpk(q1[0], q2[1]);
                a2u[8 + s][2 * h + 1] = cvtpk(q3[2], q4[3]);
            }
        }
        f32x4 sv[5];
        {
            f32x4 c0 = {0.f,0.f,0.f,0.f}, c1 = {0.f,0.f,0.f,0.f}, c2 = {0.f,0.f,0.f,0.f},
                  c3 = {0.f,0.f,0.f,0.f}, c4 = {0.f,0.f,0.f,0.f};
            #pragma unroll
            for (int s = 0; s < 2; ++s) {
                frag8 bw = w2[s];
                c0 = MFMA(bw, asfrag(a2u[0 + s]), c0);
                c1 = MFMA(bw, asfrag(a2u[2 + s]), c1);
                c2 = MFMA(bw, asfrag(a2u[4 + s]), c2);
                c3 = MFMA(bw, asfrag(a2u[6 + s]), c3);
                c4 = MFMA(bw, asfrag(a2u[8 + s]), c4);
            }
            sv[0] = (f32x4){c0[0], c1[0], c2[0], c3[0]};
            sv[1] = (f32x4){c4[0], c0[1], c1[1], c2[1]};
            sv[2] = (f32x4){c3[1], c4[1], c0[2], c1[2]};
            sv[3] = (f32x4){c2[2], c3[2], c4[2], c0[3]};
            sv[4] = (f32x4){c1[3], c2[3], c3[3], c4[3]};
        }
        __syncthreads();   // S2
        {
            const int g0 = 5 * (wv * 4 + lg);
            #pragma unroll
            for (int i = 0; i < 5; ++i)
                *(f32x4*)(smem + l15 * ST2 + (g0 + i) * 16) = sv[i];
        }
        __syncthreads();   // S3
        #pragma unroll
        for (int j = 0; j < 5; ++j) {
            int c = j * 256 + tid, r = c / 80, g = c - r * 80;
            f32x4 v = *(const f32x4*)(smem + r * ST2 + g * 16);
            *(f32x4*)(ob + (long)r * 3840 + 2560 + g * 16) = v;
        }
    }
}

extern "C" void kernel_launch(void* const* d_in, const int* in_sizes, int n_in,
                              void* d_out, int out_size, void* d_ws, size_t ws_size,
                              hipStream_t stream) {
    const float* x = (const float*)d_in[0];
    const float* w = (const float*)d_in[1];
    const float* b = (const float*)d_in[2];
    float* out = (float*)d_out;
    short* wf  = (short*)d_ws;          // 86016 bf16 = 172032 B of scratch

    hipLaunchKernelGGL(prep_kernel, dim3(336), dim3(256), 0, stream, w, wf);
    // 31250 blocks = 6250 tile groups x 5 roles
    // {fam0-32r, fam1-hi, fam1-lo, fam2-hi, fam2-lo}, role varies fastest.
    hipLaunchKernelGGL(lin_g5, dim3(31250), dim3(256), 0, stream,
                       x, wf, b, out);
}

// Round 18
// 286.720 us; speedup vs baseline: 1.0536x; 1.0536x over previous
//
#include <hip/hip_runtime.h>

// irreps linear: 256x0e + 128x1o + 64x2e, shared weights, bias on 0e.
// x: (200000, 960) f32; w: 86016 f32; b: 256 f32; out: (200000, 960) f32.
//
// FINAL (= Round 16, best measured: 287.5us, 5.34 TB/s effective, 85% of the
// 6.3 TB/s copy ceiling). Confirmed mechanisms: bf16-MFMA compute demotion;
// 32-row tiles amortizing per-block fixed costs (R13); co-temporal family
// dispatch (bid%3) merging the three families' column slices into sequential
// DRAM read/write streams (R16). R14/R15/R17 perturbations all regressed.
//
// Structure per block (one family-slice of a 32-row tile):
//   stage via global_load_lds (contiguous 1KB/row per instr, padded-stride
//   LDS, masked tails straight-line pre-S1) -> S1 -> fragments(cvt_pk) ->
//   S2 -> MFMA + piece-writes rows 0-15 -> fragments rows 16-31 -> S3 ->
//   MFMA + piece-writes rows 16-31 -> S4 -> full-line 1KB/instr stores.

typedef short frag8 __attribute__((ext_vector_type(8)));   // 8 bf16
typedef float f32x4 __attribute__((ext_vector_type(4)));
typedef unsigned int u32;
typedef u32 u32x4 __attribute__((ext_vector_type(4)));

#define ST0 1040   // 65 chunks * 16B (64 data + 1 pad)
#define ST1 1552   // 97 chunks
#define ST2 1296   // 81 chunks

static __device__ __forceinline__ short f2bf(float f) {   // prep kernel only
    union { float f; unsigned u; } v; v.f = f;
    unsigned r = (v.u + 0x7FFFu + ((v.u >> 16) & 1u)) >> 16;  // RNE
    return (short)r;
}

static __device__ __forceinline__ u32 cvtpk(float lo, float hi) {
    u32 r;
    asm("v_cvt_pk_bf16_f32 %0, %1, %2" : "=v"(r) : "v"(lo), "v"(hi));
    return r;
}

static __device__ __forceinline__ frag8 asfrag(u32x4 u) {
    union { u32x4 u; frag8 f; } t; t.u = u; return t.f;
}

#define MFMA(a, b, c) __builtin_amdgcn_mfma_f32_16x16x32_bf16((a), (b), (c), 0, 0, 0)

// ---- weight prep (validated rounds 1-17). frag f, lane l, reg j:
// k = 32*s + 4*(l>>4) + (j&3) + 16*(j>>2), w = nt*16 + (l&15).
__global__ __launch_bounds__(256) void prep_kernel(const float* __restrict__ w,
                                                   short* __restrict__ wf) {
    int e = blockIdx.x * 256 + threadIdx.x;   // 0..86015
    int f = e >> 9;
    int r = e & 511;
    int l = r >> 3, j = r & 7;
    int l15 = l & 15, lg = l >> 4;
    int kk = 4 * lg + (j & 3) + 16 * (j >> 2);
    int u, wc, woff, mul; float scale;
    if (f < 128) {
        int nt = f >> 3, s = f & 7;
        u = 32 * s + kk; wc = nt * 16 + l15; woff = 0;     mul = 256; scale = 0.0625f;
    } else if (f < 160) {
        int g = f - 128, nt = g >> 2, s = g & 3;
        u = 32 * s + kk; wc = nt * 16 + l15; woff = 65536; mul = 128; scale = 0.088388347648318447f;
    } else {
        int g = f - 160, nt = g >> 1, s = g & 1;
        u = 32 * s + kk; wc = nt * 16 + l15; woff = 81920; mul = 64;  scale = 0.125f;
    }
    wf[e] = f2bf(scale * w[woff + u * mul + wc]);
}

static __device__ __forceinline__ void gload_lds16(const void* g, void* l) {
    __builtin_amdgcn_global_load_lds(
        (const __attribute__((address_space(1))) unsigned int*)g,
        (__attribute__((address_space(3))) unsigned int*)l, 16, 0, 0);
}

__global__ __launch_bounds__(256) void lin_t32(const float* __restrict__ x,
                                               const short* __restrict__ wf,
                                               const float* __restrict__ bias,
                                               float* __restrict__ out) {
    __shared__ __align__(16) char smem[32 * ST1];   // 49664 B (max family)
    const int tid = threadIdx.x, lane = tid & 63, wv = tid >> 6;
    const int l15 = lane & 15, lg = lane >> 4;
    const int bid = blockIdx.x;
    const int fam = bid % 3;                       // family varies FASTEST
    const long rowbase = (long)(bid / 3) * 32;     // 3 fams of a tile adjacent
    const char* __restrict__ xb = (const char*)x + rowbase * 3840;
    char* __restrict__ ob = (char*)out + rowbase * 3840;
    const frag8* __restrict__ wfr = (const frag8*)wf;

    if (fam == 0) {
        // ============ family 0: cols 0..255, K=256 ============
        f32x4 bv[4];
        #pragma unroll
        for (int q = 0; q < 4; ++q)
            bv[q] = *(const f32x4*)(bias + (4 * wv + q) * 16 + 4 * lg);
        #pragma unroll
        for (int r8 = 0; r8 < 8; ++r8) {
            int r = 8 * wv + r8;
            gload_lds16(xb + (long)r * 3840 + (long)lane * 16, smem + r * ST0);
        }
        __syncthreads();   // S1: stage drained

        const char* sbA = smem + l15 * ST0;
        frag8 a0[8];
        #pragma unroll
        for (int s = 0; s < 8; ++s) {
            const f32x4 v0 = *(const f32x4*)(sbA + (8 * s + lg) * 16);
            const f32x4 v1 = *(const f32x4*)(sbA + (8 * s + 4 + lg) * 16);
            u32x4 t = { cvtpk(v0[0], v0[1]), cvtpk(v0[2], v0[3]),
                        cvtpk(v1[0], v1[1]), cvtpk(v1[2], v1[3]) };
            a0[s] = asfrag(t);
        }
        __syncthreads();   // S2: rows 0-15 reads done

        #pragma unroll
        for (int q = 0; q < 4; ++q) {
            const int nt = 4 * wv + q;
            f32x4 acc = {0.f, 0.f, 0.f, 0.f};
            #pragma unroll
            for (int s = 0; s < 8; ++s)
                acc = MFMA(wfr[(nt * 8 + s) * 64 + lane], a0[s], acc);
            const int g0 = nt * 4 + lg;
            *(f32x4*)(smem + l15 * ST0 + g0 * 16) = acc + bv[q];
        }
        const char* sbB = smem + (16 + l15) * ST0;
        frag8 a0b[8];
        #pragma unroll
        for (int s = 0; s < 8; ++s) {
            const f32x4 v0 = *(const f32x4*)(sbB + (8 * s + lg) * 16);
            const f32x4 v1 = *(const f32x4*)(sbB + (8 * s + 4 + lg) * 16);
            u32x4 t = { cvtpk(v0[0], v0[1]), cvtpk(v0[2], v0[3]),
                        cvtpk(v1[0], v1[1]), cvtpk(v1[2], v1[3]) };
            a0b[s] = asfrag(t);
        }
        __syncthreads();   // S3: rows 16-31 reads done

        #pragma unroll
        for (int q = 0; q < 4; ++q) {
            const int nt = 4 * wv + q;
            f32x4 acc = {0.f, 0.f, 0.f, 0.f};
            #pragma unroll
            for (int s = 0; s < 8; ++s)
                acc = MFMA(wfr[(nt * 8 + s) * 64 + lane], a0b[s], acc);
            const int g0 = nt * 4 + lg;
            *(f32x4*)(smem + (16 + l15) * ST0 + g0 * 16) = acc + bv[q];
        }
        __syncthreads();   // S4: all pieces written

        #pragma unroll
        for (int j = 0; j < 8; ++j) {
            int c = j * 256 + tid, r = c >> 6, g = c & 63;
            f32x4 v = *(const f32x4*)(smem + r * ST0 + g * 16);
            *(f32x4*)(ob + (long)r * 3840 + g * 16) = v;
        }
    } else if (fam == 1) {
        // ======= family 1: cols 256..639 (col = 256+3u+i), K=128 =======
        frag8 w1[8];   // weights in regs, reused across both subtiles
        #pragma unroll
        for (int q = 0; q < 2; ++q)
            #pragma unroll
            for (int s = 0; s < 4; ++s)
                w1[q * 4 + s] = wfr[(128 + (2 * wv + q) * 4 + s) * 64 + lane];

        #pragma unroll
        for (int r8 = 0; r8 < 8; ++r8) {
            int r = 8 * wv + r8;
            gload_lds16(xb + (long)r * 3840 + 1024 + (long)lane * 16, smem + r * ST1);
            if (lane < 32)
                gload_lds16(xb + (long)r * 3840 + 2048 + (long)lane * 16,
                            smem + r * ST1 + 1024);
        }
        __syncthreads();   // S1

        // ---- subtile A ----
        {
            const char* sb = smem + l15 * ST1;
            u32x4 a1u[12];
            #pragma unroll
            for (int s = 0; s < 4; ++s) {
                #pragma unroll
                for (int h = 0; h < 2; ++h) {
                    const int cb = 24 * s + 12 * h + 3 * lg;
                    const f32x4 q0 = *(const f32x4*)(sb + (cb    ) * 16);
                    const f32x4 q1 = *(const f32x4*)(sb + (cb + 1) * 16);
                    const f32x4 q2 = *(const f32x4*)(sb + (cb + 2) * 16);
                    a1u[0 + s][2 * h]     = cvtpk(q0[0], q0[3]);
                    a1u[0 + s][2 * h + 1] = cvtpk(q1[2], q2[1]);
                    a1u[4 + s][2 * h]     = cvtpk(q0[1], q1[0]);
                    a1u[4 + s][2 * h + 1] = cvtpk(q1[3], q2[2]);
                    a1u[8 + s][2 * h]     = cvtpk(q0[2], q1[1]);
                    a1u[8 + s][2 * h + 1] = cvtpk(q2[0], q2[3]);
                }
            }
            __syncthreads();   // S2: rows 0-15 reads done
            #pragma unroll
            for (int q = 0; q < 2; ++q) {
                const int nt = 2 * wv + q;
                f32x4 c0 = {0.f,0.f,0.f,0.f}, c1 = {0.f,0.f,0.f,0.f}, c2 = {0.f,0.f,0.f,0.f};
                #pragma unroll
                for (int s = 0; s < 4; ++s) {
                    frag8 bw = w1[q * 4 + s];
                    c0 = MFMA(bw, asfrag(a1u[0 + s]), c0);
                    c1 = MFMA(bw, asfrag(a1u[4 + s]), c1);
                    c2 = MFMA(bw, asfrag(a1u[8 + s]), c2);
                }
                const int g0 = 3 * (nt * 4 + lg);
                char* wb = smem + l15 * ST1;
                *(f32x4*)(wb + (g0    ) * 16) = (f32x4){c0[0], c1[0], c2[0], c0[1]};
                *(f32x4*)(wb + (g0 + 1) * 16) = (f32x4){c1[1], c2[1], c0[2], c1[2]};
                *(f32x4*)(wb + (g0 + 2) * 16) = (f32x4){c2[2], c0[3], c1[3], c2[3]};
            }
        }
        // ---- subtile B (rows 16-31, disjoint from piece-A) ----
        {
            const char* sb = smem + (16 + l15) * ST1;
            u32x4 a1u[12];
            #pragma unroll
            for (int s = 0; s < 4; ++s) {
                #pragma unroll
                for (int h = 0; h < 2; ++h) {
                    const int cb = 24 * s + 12 * h + 3 * lg;
                    const f32x4 q0 = *(const f32x4*)(sb + (cb    ) * 16);
                    const f32x4 q1 = *(const f32x4*)(sb + (cb + 1) * 16);
                    const f32x4 q2 = *(const f32x4*)(sb + (cb + 2) * 16);
                    a1u[0 + s][2 * h]     = cvtpk(q0[0], q0[3]);
                    a1u[0 + s][2 * h + 1] = cvtpk(q1[2], q2[1]);
                    a1u[4 + s][2 * h]     = cvtpk(q0[1], q1[0]);
                    a1u[4 + s][2 * h + 1] = cvtpk(q1[3], q2[2]);
                    a1u[8 + s][2 * h]     = cvtpk(q0[2], q1[1]);
                    a1u[8 + s][2 * h + 1] = cvtpk(q2[0], q2[3]);
                }
            }
            __syncthreads();   // S3: rows 16-31 reads done
            #pragma unroll
            for (int q = 0; q < 2; ++q) {
                const int nt = 2 * wv + q;
                f32x4 c0 = {0.f,0.f,0.f,0.f}, c1 = {0.f,0.f,0.f,0.f}, c2 = {0.f,0.f,0.f,0.f};
                #pragma unroll
                for (int s = 0; s < 4; ++s) {
                    frag8 bw = w1[q * 4 + s];
                    c0 = MFMA(bw, asfrag(a1u[0 + s]), c0);
                    c1 = MFMA(bw, asfrag(a1u[4 + s]), c1);
                    c2 = MFMA(bw, asfrag(a1u[8 + s]), c2);
                }
                const int g0 = 3 * (nt * 4 + lg);
                char* wb = smem + (16 + l15) * ST1;
                *(f32x4*)(wb + (g0    ) * 16) = (f32x4){c0[0], c1[0], c2[0], c0[1]};
                *(f32x4*)(wb + (g0 + 1) * 16) = (f32x4){c1[1], c2[1], c0[2], c1[2]};
                *(f32x4*)(wb + (g0 + 2) * 16) = (f32x4){c2[2], c0[3], c1[3], c2[3]};
            }
        }
        __syncthreads();   // S4
        #pragma unroll
        for (int j = 0; j < 12; ++j) {
            int c = j * 256 + tid, r = c / 96, g = c - r * 96;
            f32x4 v = *(const f32x4*)(smem + r * ST1 + g * 16);
            *(f32x4*)(ob + (long)r * 3840 + 1024 + g * 16) = v;
        }
    } else {
        // ======= family 2: cols 640..959 (col = 640+5u+i), K=64 =======
        frag8 w2[2];
        #pragma unroll
        for (int s = 0; s < 2; ++s)
            w2[s] = wfr[(160 + wv * 2 + s) * 64 + lane];

        #pragma unroll
        for (int r8 = 0; r8 < 8; ++r8) {
            int r = 8 * wv + r8;
            gload_lds16(xb + (long)r * 3840 + 2560 + (long)lane * 16, smem + r * ST2);
            if (lane < 16)
                gload_lds16(xb + (long)r * 3840 + 3584 + (long)lane * 16,
                            smem + r * ST2 + 1024);
        }
        __syncthreads();   // S1

        #pragma unroll
        for (int half = 0; half < 2; ++half) {
            const int rbase = 16 * half;
            const char* sb = smem + (rbase + l15) * ST2;
            u32x4 a2u[10];
            #pragma unroll
            for (int s = 0; s < 2; ++s) {
                #pragma unroll
                for (int h = 0; h < 2; ++h) {
                    const int cb = 40 * s + 20 * h + 5 * lg;
                    const f32x4 q0 = *(const f32x4*)(sb + (cb    ) * 16);
                    const f32x4 q1 = *(const f32x4*)(sb + (cb + 1) * 16);
                    const f32x4 q2 = *(const f32x4*)(sb + (cb + 2) * 16);
                    const f32x4 q3 = *(const f32x4*)(sb + (cb + 3) * 16);
                    const f32x4 q4 = *(const f32x4*)(sb + (cb + 4) * 16);
                    a2u[0 + s][2 * h]     = cvtpk(q0[0], q1[1]);
                    a2u[0 + s][2 * h + 1] = cvtpk(q2[2], q3[3]);
                    a2u[2 + s][2 * h]     = cvtpk(q0[1], q1[2]);
                    a2u[2 + s][2 * h + 1] = cvtpk(q2[3], q4[0]);
                    a2u[4 + s][2 * h]     = cvtpk(q0[2], q1[3]);
                    a2u[4 + s][2 * h + 1] = cvtpk(q3[0], q4[1]);
                    a2u[6 + s][2 * h]     = cvtpk(q0[3], q2[0]);
                    a2u[6 + s][2 * h + 1] = cvtpk(q3[1], q4[2]);
                    a2u[8 + s][2 * h]     = cvtpk(q1[0], q2[1]);
                    a2u[8 + s][2 * h + 1] = cvtpk(q3[2], q4[3]);
                }
            }
            __syncthreads();   // S2/S3: this half's reads done
            {
                f32x4 c0 = {0.f,0.f,0.f,0.f}, c1 = {0.f,0.f,0.f,0.f}, c2 = {0.f,0.f,0.f,0.f},
                      c3 = {0.f,0.f,0.f,0.f}, c4 = {0.f,0.f,0.f,0.f};
                #pragma unroll
                for (int s = 0; s < 2; ++s) {
                    frag8 bw = w2[s];
                    c0 = MFMA(bw, asfrag(a2u[0 + s]), c0);
                    c1 = MFMA(bw, asfrag(a2u[2 + s]), c1);
                    c2 = MFMA(bw, asfrag(a2u[4 + s]), c2);
                    c3 = MFMA(bw, asfrag(a2u[6 + s]), c3);
                    c4 = MFMA(bw, asfrag(a2u[8 + s]), c4);
                }
                const int g0 = 5 * (wv * 4 + lg);
                char* wb = smem + (rbase + l15) * ST2;
                *(f32x4*)(wb + (g0    ) * 16) = (f32x4){c0[0], c1[0], c2[0], c3[0]};
                *(f32x4*)(wb + (g0 + 1) * 16) = (f32x4){c4[0], c0[1], c1[1], c2[1]};
                *(f32x4*)(wb + (g0 + 2) * 16) = (f32x4){c3[1], c4[1], c0[2], c1[2]};
                *(f32x4*)(wb + (g0 + 3) * 16) = (f32x4){c2[2], c3[2], c4[2], c0[3]};
                *(f32x4*)(wb + (g0 + 4) * 16) = (f32x4){c1[3], c2[3], c3[3], c4[3]};
            }
        }
        __syncthreads();   // S4
        #pragma unroll
        for (int j = 0; j < 10; ++j) {
            int c = j * 256 + tid, r = c / 80, g = c - r * 80;
            f32x4 v = *(const f32x4*)(smem + r * ST2 + g * 16);
            *(f32x4*)(ob + (long)r * 3840 + 2560 + g * 16) = v;
        }
    }
}

extern "C" void kernel_launch(void* const* d_in, const int* in_sizes, int n_in,
                              void* d_out, int out_size, void* d_ws, size_t ws_size,
                              hipStream_t stream) {
    const float* x = (const float*)d_in[0];
    const float* w = (const float*)d_in[1];
    const float* b = (const float*)d_in[2];
    float* out = (float*)d_out;
    short* wf  = (short*)d_ws;          // 86016 bf16 = 172032 B of scratch

    hipLaunchKernelGGL(prep_kernel, dim3(336), dim3(256), 0, stream, w, wf);
    // 18750 blocks = 6250 tiles x 3 families, family varies fastest so the
    // 3 column-slices of each 32-row tile are read/written co-temporally.
    hipLaunchKernelGGL(lin_t32, dim3(18750), dim3(256), 0, stream,
                       x, wf, b, out);
}